// Round 28
// baseline (164.080 us; speedup 1.0000x reference)
//
#include <hip/hip_runtime.h>
#include <math.h>

#define NN 50000
#define NE 800000

typedef __attribute__((ext_vector_type(8))) short short8;
typedef __attribute__((ext_vector_type(8))) unsigned short ushort8;
typedef __attribute__((ext_vector_type(4))) float f32x4;

#define QENC 31.75f            // 127/4
#define QDEC 0.031496063f      // 4/127

// workspace layout (offsets in 4-byte words) -- node-major tensors
#define OFF_DEG    0          // float[NN] -> dinv (written by k_colA)
#define OFF_BSUM   50000      // int[256]
#define OFF_ROWPTR 100000     // int[NN+1]
#define OFF_WB     200072     // ushort[192*512] fragment-major Wb2
#define OFF_BIAS   249224     // float[256]
#define OFF_ELIST  249480     // uint[NE]
#define OFF_XB     1849480    // ushort[NN*64] node-major, 1.6M words each
#define OFF_HB     3449480
#define OFF_T1X    5049480
#define OFF_T1H    6649480
#define OFF_T2X    8249480
#define OFF_T2H    9849480
#define OFF_XH8    11449480   // char[NN*128] int8 interleaved X|H
#define OFF_T1XH8  13049480   // char[NN*128] int8 interleaved T1X|T1H
// overlays (consumed before their hosts are written):
#define OFF_HISTP  5049480    // uchar[250][50000] over T1X+T1H
#define OFF_COLEXC 8249480    // uchar[250][50000] over T2X+T2H
#define OFF_DEGP   13049480   // float[32][50000] over T1XH8

#define DCH    250            // dst chunks of 3200 edges
#define DCHUNK 3200
#define SCH    32             // deg chunks of 25000 edges
#define SCHUNK 25000
#define CNBLK  196
#define CBLK   1563
#define WBLK   48
#define FR_HIST (2 * DCH)              // 500
#define FR_DEG  (FR_HIST + 8 * SCH)    // 756
#define FR_CVT  (FR_DEG + CBLK)        // 2319
#define FR_ALL  (FR_CVT + WBLK)        // 2367

__device__ inline unsigned short f2bf(float f) {
  union { float f; unsigned u; } v; v.f = f;
  unsigned u = v.u;
  return (unsigned short)((u + 0x7FFFu + ((u >> 16) & 1u)) >> 16);
}
__device__ inline float bf2f(unsigned short u) {
  return __uint_as_float(((unsigned)u) << 16);
}
__device__ inline float sigm(float x) { return 1.f / (1.f + __expf(-x)); }
__device__ inline float tanh_(float x) { return 1.f - 2.f / (__expf(2.f * x) + 1.f); }

// signed int8 encode, fixed scale 4/127
__device__ inline unsigned f2q8(float f) {
  float c = fminf(fmaxf(f * QENC, -127.f), 127.f);
  int q = (int)rintf(c);
  return (unsigned)(q & 0xff);
}

// merged front-end: dst-hist + src-deg + cvt + wconv, one launch.
__global__ __launch_bounds__(256) void k_front(
    const int* __restrict__ src, const int* __restrict__ dst,
    const float* __restrict__ w,
    unsigned char* __restrict__ histp, float* __restrict__ degp,
    const float* __restrict__ X, const float* __restrict__ H,
    unsigned short* __restrict__ Xb, unsigned short* __restrict__ Hb,
    unsigned char* __restrict__ XH8,
    const float* __restrict__ Wx, const float* __restrict__ Wh,
    const float* __restrict__ bx, const float* __restrict__ bh,
    const float* __restrict__ bg,
    unsigned short* __restrict__ Wb2, float* __restrict__ bias) {
  __shared__ unsigned lds[6250];  // 25 KB (hist/deg roles only)
  const int t = threadIdx.x;
  const int bid = blockIdx.x;
  if (bid < FR_HIST) {
    const int c = bid >> 1, half = bid & 1, lo = half * 25000;
    for (int i = t; i < 6250; i += 256) lds[i] = 0u;
    __syncthreads();
    const int4* d4 = (const int4*)(dst + c * DCHUNK);
#pragma unroll
    for (int it = 0; it < 4; ++it) {
      int o4 = it * 256 + t;
      if (o4 < DCHUNK / 4) {
        int4 dv = d4[o4];
        int ds[4] = {dv.x, dv.y, dv.z, dv.w};
#pragma unroll
        for (int j = 0; j < 4; ++j) {
          int dr = ds[j] - lo;
          if ((unsigned)dr < 25000u)
            atomicAdd(&lds[dr >> 2], 1u << ((dr & 3) * 8));
        }
      }
    }
    __syncthreads();
    unsigned* hw = (unsigned*)(histp + c * 50000 + lo);
    for (int i = t; i < 6250; i += 256) hw[i] = lds[i];
  } else if (bid < FR_DEG) {
    const int idx = bid - FR_HIST;
    const int c = idx >> 3, e8 = idx & 7, lo = e8 * 6250;
    float* ldsf = (float*)lds;
    for (int i = t; i < 6250; i += 256) ldsf[i] = 0.f;
    __syncthreads();
    const int4* s4 = (const int4*)(src + c * SCHUNK);
    const float4* w4 = (const float4*)(w + c * SCHUNK);
    for (int it = 0; it < 25; ++it) {
      int o4 = it * 256 + t;
      if (o4 < SCHUNK / 4) {
        int4 sv = s4[o4];
        float4 wv = w4[o4];
        int ss[4] = {sv.x, sv.y, sv.z, sv.w};
        float ww[4] = {wv.x, wv.y, wv.z, wv.w};
#pragma unroll
        for (int j = 0; j < 4; ++j) {
          int sr = ss[j] - lo;
          if ((unsigned)sr < 6250u) atomicAdd(&ldsf[sr], ww[j]);
        }
      }
    }
    __syncthreads();
    float* dw = degp + c * 50000 + lo;
    for (int i = t; i < 6250; i += 256) dw[i] = ldsf[i];
  } else if (bid < FR_CVT) {
    int i = ((bid - FR_DEG) * 256 + t) * 8;
    if (i >= NN * 64) return;
    float4 x0 = *(const float4*)&X[i];
    float4 x1 = *(const float4*)&X[i + 4];
    float4 h0 = *(const float4*)&H[i];
    float4 h1 = *(const float4*)&H[i + 4];
    ushort8 xb, hb;
    xb[0] = f2bf(x0.x); xb[1] = f2bf(x0.y); xb[2] = f2bf(x0.z); xb[3] = f2bf(x0.w);
    xb[4] = f2bf(x1.x); xb[5] = f2bf(x1.y); xb[6] = f2bf(x1.z); xb[7] = f2bf(x1.w);
    hb[0] = f2bf(h0.x); hb[1] = f2bf(h0.y); hb[2] = f2bf(h0.z); hb[3] = f2bf(h0.w);
    hb[4] = f2bf(h1.x); hb[5] = f2bf(h1.y); hb[6] = f2bf(h1.z); hb[7] = f2bf(h1.w);
    *(ushort8*)&Xb[i] = xb;
    *(ushort8*)&Hb[i] = hb;
    int n = i >> 6, c = i & 63;
    unsigned xlo = f2q8(x0.x) | (f2q8(x0.y) << 8) | (f2q8(x0.z) << 16) | (f2q8(x0.w) << 24);
    unsigned xhi = f2q8(x1.x) | (f2q8(x1.y) << 8) | (f2q8(x1.z) << 16) | (f2q8(x1.w) << 24);
    unsigned hlo = f2q8(h0.x) | (f2q8(h0.y) << 8) | (f2q8(h0.z) << 16) | (f2q8(h0.w) << 24);
    unsigned hhi = f2q8(h1.x) | (f2q8(h1.y) << 8) | (f2q8(h1.z) << 16) | (f2q8(h1.w) << 24);
    *(uint2*)&XH8[n * 128 + c] = make_uint2(xlo, xhi);
    *(uint2*)&XH8[n * 128 + 64 + c] = make_uint2(hlo, hhi);
  } else {
    int idx = (bid - FR_CVT) * 256 + t;
    if (idx < 256) bias[idx] = bx[idx] + bh[idx] + bg[idx];
    if (idx >= 192 * 64) return;
    int word = idx >> 6, l = idx & 63;
    int cw = word & 3;
    int gk = word >> 2;
    int g = gk / 12, kc = gk - g * 12;
    int col = cw * 16 + (l & 15);
    int seg = kc >> 1;
    int kbase = (kc & 1) * 32 + (l >> 4) * 8;
    const float* Wsel = (seg < 3) ? Wx : Wh;
    int sch = (seg < 3) ? seg : seg - 3;
    ushort8 o8;
#pragma unroll
    for (int j = 0; j < 8; ++j) {
      float v = Wsel[((g * 3 + sch) * 64 + kbase + j) * 64 + col];
      o8[j] = f2bf(v);
    }
    *(ushort8*)&Wb2[idx * 8] = o8;
  }
}

__global__ __launch_bounds__(256) void k_colA(
    const unsigned char* __restrict__ histp, unsigned char* __restrict__ colexc,
    const float* __restrict__ degp, int* __restrict__ rowptr,
    int* __restrict__ bsum, float* __restrict__ dinv) {
  __shared__ int wsum[4];
  const int t = threadIdx.x, lane = t & 63, w = t >> 6;
  const int bin = blockIdx.x * 256 + t;
  int acc = 0;
  if (bin < NN) {
#pragma unroll 10
    for (int b = 0; b < DCH; ++b) {
      unsigned char c = histp[b * 50000 + bin];
      colexc[b * 50000 + bin] = (unsigned char)acc;
      acc += c;
    }
    float dacc = 0.f;
#pragma unroll 8
    for (int b = 0; b < SCH; ++b) dacc += degp[b * 50000 + bin];
    dinv[bin] = (dacc > 0.f) ? rsqrtf(dacc) : 0.f;
  }
  int val = acc;
#pragma unroll
  for (int off = 1; off < 64; off <<= 1) {
    int u = __shfl_up(val, off, 64);
    if (lane >= off) val += u;
  }
  if (lane == 63) wsum[w] = val;
  __syncthreads();
  int wb = 0;
#pragma unroll
  for (int i = 0; i < 4; ++i) wb += (i < w) ? wsum[i] : 0;
  int incl = wb + val;
  if (bin < NN) rowptr[bin + 1] = incl;
  if (t == 255) bsum[blockIdx.x] = incl;
}

__global__ __launch_bounds__(256) void k_scanB2(int* __restrict__ bsum,
                                                int* __restrict__ rowptr) {
  __shared__ int wsum[4];
  const int t = threadIdx.x, lane = t & 63, w = t >> 6;
  int v = (t < CNBLK) ? bsum[t] : 0;
  int val = v;
#pragma unroll
  for (int off = 1; off < 64; off <<= 1) {
    int u = __shfl_up(val, off, 64);
    if (lane >= off) val += u;
  }
  if (lane == 63) wsum[w] = val;
  __syncthreads();
  int wb = 0;
#pragma unroll
  for (int i = 0; i < 4; ++i) wb += (i < w) ? wsum[i] : 0;
  int incl = wb + val;
  if (t < CNBLK) bsum[t] = incl - v;
  if (t == 0) rowptr[0] = 0;
}

__global__ __launch_bounds__(256) void k_scanC2(int* __restrict__ rowptr,
                                                const int* __restrict__ bsum) {
  int i = blockIdx.x * 256 + threadIdx.x;
  if (i < NN) rowptr[i + 1] += bsum[blockIdx.x];
}

__global__ __launch_bounds__(256) void k_scat(
    const int* __restrict__ src, const int* __restrict__ dst,
    const float* __restrict__ w, const float* __restrict__ dinv,
    const int* __restrict__ rowptr, const unsigned char* __restrict__ colexc,
    unsigned* __restrict__ elist) {
  __shared__ unsigned lds[6250];
  const int t = threadIdx.x, bid = blockIdx.x;
  const int c = bid >> 1, half = bid & 1, lo = half * 25000;
  for (int i = t; i < 6250; i += 256) lds[i] = 0u;
  __syncthreads();
  const int4* s4 = (const int4*)(src + c * DCHUNK);
  const int4* d4 = (const int4*)(dst + c * DCHUNK);
  const float4* w4 = (const float4*)(w + c * DCHUNK);
#pragma unroll
  for (int it = 0; it < 4; ++it) {
    int o4 = it * 256 + t;
    if (o4 < DCHUNK / 4) {
      int4 sv = s4[o4];
      int4 dv = d4[o4];
      float4 wv = w4[o4];
      int ss[4] = {sv.x, sv.y, sv.z, sv.w};
      int dd[4] = {dv.x, dv.y, dv.z, dv.w};
      float ww[4] = {wv.x, wv.y, wv.z, wv.w};
#pragma unroll
      for (int j = 0; j < 4; ++j) {
        int d = dd[j];
        int dr = d - lo;
        if ((unsigned)dr < 25000u) {
          int s = ss[j];
          float nm = -dinv[s] * ww[j] * dinv[d];
          unsigned old = atomicAdd(&lds[dr >> 2], 1u << ((dr & 3) * 8));
          int rank = (int)((old >> ((dr & 3) * 8)) & 0xffu);
          int pos = rowptr[d] + (int)colexc[c * 50000 + d] + rank;
          elist[pos] = (((unsigned)f2bf(nm)) << 16) | (unsigned)s;
        }
      }
    }
  }
}

// prop (R21-proven): signed int8 interleaved gather, 8 edges/instr.
__global__ __launch_bounds__(256) void k_prop(
    const int* __restrict__ rowptr, const unsigned* __restrict__ elist,
    const uint4* __restrict__ inP8,
    unsigned short* __restrict__ outX, unsigned short* __restrict__ outH,
    uint4* __restrict__ outP8,
    const unsigned short* __restrict__ baseX, const unsigned short* __restrict__ baseH,
    int mode) {
  const int n = blockIdx.x * 4 + (threadIdx.x >> 6);
  const int l = threadIdx.x & 63;
  const int es = l >> 3;
  const int p = l & 7;
  if (n >= NN) return;
  const int beg = rowptr[n], end = rowptr[n + 1];
  float acc[16];
#pragma unroll
  for (int j = 0; j < 16; ++j) acc[j] = 0.f;
  for (int i0 = beg; i0 < end; i0 += 16) {
    int ie0 = i0 + es, ie1 = i0 + 8 + es;
    unsigned u0 = (ie0 < end) ? elist[ie0] : 0u;
    unsigned u1 = (ie1 < end) ? elist[ie1] : 0u;
    int s0 = (int)(u0 & 0xffffu), s1 = (int)(u1 & 0xffffu);
    float n0 = __uint_as_float(u0 & 0xffff0000u) * QDEC;
    float n1 = __uint_as_float(u1 & 0xffff0000u) * QDEC;
    uint4 v0 = inP8[s0 * 8 + p];
    uint4 v1 = inP8[s1 * 8 + p];
    unsigned w0[4] = {v0.x, v0.y, v0.z, v0.w};
    unsigned w1[4] = {v1.x, v1.y, v1.z, v1.w};
#pragma unroll
    for (int wd = 0; wd < 4; ++wd) {
#pragma unroll
      for (int bt = 0; bt < 4; ++bt) {
        float g0 = (float)((int)(char)(w0[wd] >> (bt * 8)));
        float g1 = (float)((int)(char)(w1[wd] >> (bt * 8)));
        acc[wd * 4 + bt] += n0 * g0 + n1 * g1;
      }
    }
  }
#pragma unroll
  for (int mask = 8; mask <= 32; mask <<= 1)
#pragma unroll
    for (int j = 0; j < 16; ++j) acc[j] += __shfl_xor(acc[j], mask, 64);

  if (es != 0) return;
  const int chbase = (p & 3) * 16;
  unsigned short* outT = (p < 4) ? outX : outH;
  const unsigned short* baseT = (p < 4) ? baseX : baseH;
  float vals[16];
  if (mode) {
    ushort8 b0 = *(const ushort8*)&baseT[n * 64 + chbase];
    ushort8 b1 = *(const ushort8*)&baseT[n * 64 + chbase + 8];
#pragma unroll
    for (int j = 0; j < 8; ++j) {
      vals[j] = 2.f * acc[j] - bf2f(b0[j]);
      vals[8 + j] = 2.f * acc[8 + j] - bf2f(b1[j]);
    }
  } else {
#pragma unroll
    for (int j = 0; j < 16; ++j) vals[j] = acc[j];
  }
  ushort8 o0, o1;
#pragma unroll
  for (int j = 0; j < 8; ++j) { o0[j] = f2bf(vals[j]); o1[j] = f2bf(vals[8 + j]); }
  *(ushort8*)&outT[n * 64 + chbase] = o0;
  *(ushort8*)&outT[n * 64 + chbase + 8] = o1;
  if (!mode) {
    unsigned wv[4];
#pragma unroll
    for (int wd = 0; wd < 4; ++wd) {
      unsigned r = 0;
#pragma unroll
      for (int bt = 0; bt < 4; ++bt) r |= f2q8(vals[wd * 4 + bt]) << (bt * 8);
      wv[wd] = r;
    }
    uint4 o8; o8.x = wv[0]; o8.y = wv[1]; o8.z = wv[2]; o8.w = wv[3];
    outP8[n * 8 + p] = o8;
  }
}

// MFMA gates (R21-proven): 32-row tiles, 24KB LDS stage (swizzled), node-major
// A, fragment-major B, C prefetched, epilogue in registers.
__global__ __launch_bounds__(256, 6) void k_gates(
    const unsigned short* __restrict__ Xb, const unsigned short* __restrict__ Hb,
    const unsigned short* __restrict__ T1X, const unsigned short* __restrict__ T1H,
    const unsigned short* __restrict__ T2X, const unsigned short* __restrict__ T2H,
    const unsigned short* __restrict__ Wb2, const float* __restrict__ C,
    const float* __restrict__ bias, const float* __restrict__ wc,
    float* __restrict__ out) {
  __shared__ unsigned short A[6 * 32 * 64];  // 24 KB
  const int t = threadIdx.x;
  const int cw = t >> 6;
  const int l = t & 63;
  const int base = blockIdx.x * 32;
  const int lr = l & 15;
  const int cc = cw * 16 + lr;

  float cpre[2][4];
#pragma unroll
  for (int rb = 0; rb < 2; ++rb)
#pragma unroll
    for (int q = 0; q < 4; ++q) {
      int n = base + rb * 16 + (l >> 4) * 4 + q;
      int nc = (n < NN) ? n : NN - 1;
      cpre[rb][q] = C[nc * 64 + cc];
    }

  const unsigned short* segp[6] = {Xb, T1X, T2X, Hb, T1H, T2H};
  {
    const int r = t >> 3, g0 = t & 7;
    const int gsw = g0 ^ (r & 7);
    int n = base + r;
    int nc = (n < NN) ? n : NN - 1;
    ushort8 st[6];
#pragma unroll
    for (int seg = 0; seg < 6; ++seg)
      st[seg] = *(const ushort8*)&segp[seg][nc * 64 + gsw * 8];
#pragma unroll
    for (int seg = 0; seg < 6; ++seg)
      *(ushort8*)&A[(seg * 256 + t) * 8] = st[seg];
  }
  __syncthreads();

  f32x4 acc[4][2];
#pragma unroll
  for (int g = 0; g < 4; ++g) {
    acc[g][0] = (f32x4){0.f, 0.f, 0.f, 0.f};
    acc[g][1] = (f32x4){0.f, 0.f, 0.f, 0.f};
  }

#pragma unroll
  for (int kc = 0; kc < 12; ++kc) {
    const int seg = kc >> 1;
    const int slot = ((kc & 1) * 4 + (l >> 4)) ^ (lr & 7);
    short8 a[2];
#pragma unroll
    for (int rb = 0; rb < 2; ++rb) {
      int row = rb * 16 + lr;
      a[rb] = *(const short8*)&A[((seg * 32 + row) * 8 + slot) * 8];
    }
#pragma unroll
    for (int g = 0; g < 4; ++g) {
      short8 b = *(const short8*)&Wb2[(((g * 12 + kc) * 4 + cw) << 9) + l * 8];
      acc[g][0] = __builtin_amdgcn_mfma_f32_16x16x32_bf16(a[0], b, acc[g][0], 0, 0, 0);
      acc[g][1] = __builtin_amdgcn_mfma_f32_16x16x32_bf16(a[1], b, acc[g][1], 0, 0, 0);
    }
  }

  const float bI = bias[cc],       bF = bias[64 + cc];
  const float bT = bias[128 + cc], bO = bias[192 + cc];
  const float wI = wc[cc], wF = wc[64 + cc], wO = wc[128 + cc];
#pragma unroll
  for (int rb = 0; rb < 2; ++rb) {
#pragma unroll
    for (int q = 0; q < 4; ++q) {
      int n = base + rb * 16 + (l >> 4) * 4 + q;
      if (n >= NN) continue;
      float cv = cpre[rb][q];
      float pI = acc[0][rb][q] + bI + wI * cv;
      float pF = acc[1][rb][q] + bF + wF * cv;
      float pT = acc[2][rb][q] + bT;
      float I = sigm(pI);
      float F = sigm(pF);
      float T = tanh_(pT);
      float Cn = F * cv + I * T;
      float pO = acc[3][rb][q] + bO + wO * Cn;
      float O = sigm(pO);
      out[n * 64 + cc] = O * tanh_(Cn);
      out[NN * 64 + n * 64 + cc] = Cn;
    }
  }
}

extern "C" void kernel_launch(void* const* d_in, const int* in_sizes, int n_in,
                              void* d_out, int out_size, void* d_ws, size_t ws_size,
                              hipStream_t stream) {
  const float* X  = (const float*)d_in[0];
  const int*   ei = (const int*)d_in[1];
  const float* ew = (const float*)d_in[2];
  const float* H  = (const float*)d_in[3];
  const float* C  = (const float*)d_in[4];
  const float* Wx = (const float*)d_in[5];
  const float* bx = (const float*)d_in[6];
  const float* Wh = (const float*)d_in[7];
  const float* bh = (const float*)d_in[8];
  const float* wc = (const float*)d_in[9];
  const float* bg = (const float*)d_in[10];
  float* out = (float*)d_out;
  float* ws = (float*)d_ws;

  const int* src = ei;
  const int* dst = ei + NE;
  float* dinv = ws + OFF_DEG;
  int* bsum = (int*)(ws + OFF_BSUM);
  int* rowptr = (int*)(ws + OFF_ROWPTR);
  unsigned short* Wb2 = (unsigned short*)(ws + OFF_WB);
  float* bias = ws + OFF_BIAS;
  unsigned* elist = (unsigned*)(ws + OFF_ELIST);
  unsigned char* histp = (unsigned char*)(ws + OFF_HISTP);
  unsigned char* colexc = (unsigned char*)(ws + OFF_COLEXC);
  float* degp = ws + OFF_DEGP;
  unsigned short* Xb  = (unsigned short*)(ws + OFF_XB);
  unsigned short* Hb  = (unsigned short*)(ws + OFF_HB);
  unsigned short* T1X = (unsigned short*)(ws + OFF_T1X);
  unsigned short* T1H = (unsigned short*)(ws + OFF_T1H);
  unsigned short* T2X = (unsigned short*)(ws + OFF_T2X);
  unsigned short* T2H = (unsigned short*)(ws + OFF_T2H);
  unsigned char* XH8   = (unsigned char*)(ws + OFF_XH8);
  unsigned char* T1XH8 = (unsigned char*)(ws + OFF_T1XH8);

  k_front<<<FR_ALL, 256, 0, stream>>>(src, dst, ew, histp, degp,
                                      X, H, Xb, Hb, XH8,
                                      Wx, Wh, bx, bh, bg, Wb2, bias);
  k_colA<<<CNBLK, 256, 0, stream>>>(histp, colexc, degp, rowptr, bsum, dinv);
  k_scanB2<<<1, 256, 0, stream>>>(bsum, rowptr);
  k_scanC2<<<CNBLK, 256, 0, stream>>>(rowptr, bsum);
  k_scat<<<2 * DCH, 256, 0, stream>>>(src, dst, ew, dinv, rowptr, colexc, elist);
  k_prop<<<NN / 4, 256, 0, stream>>>(rowptr, elist, (const uint4*)XH8,
                                     T1X, T1H, (uint4*)T1XH8,
                                     nullptr, nullptr, 0);
  k_prop<<<NN / 4, 256, 0, stream>>>(rowptr, elist, (const uint4*)T1XH8,
                                     T2X, T2H, nullptr, Xb, Hb, 1);
  k_gates<<<(NN + 31) / 32, 256, 0, stream>>>(Xb, Hb, T1X, T1H, T2X, T2H,
                                              Wb2, C, bias, wc, out);
}

// Round 29
// 163.360 us; speedup vs baseline: 1.0044x; 1.0044x over previous
//
#include <hip/hip_runtime.h>
#include <math.h>

#define NN 50000
#define NE 800000

typedef __attribute__((ext_vector_type(8))) short short8;
typedef __attribute__((ext_vector_type(8))) unsigned short ushort8;
typedef __attribute__((ext_vector_type(4))) float f32x4;

#define QENC 31.75f            // 127/4
#define QDEC 0.031496063f      // 4/127

// workspace layout (offsets in 4-byte words) -- node-major tensors
#define OFF_DEG    0          // float[NN] -> dinv (written by k_colA)
#define OFF_BSUM   50000      // int[256]
#define OFF_ROWPTR 100000     // int[NN+1]
#define OFF_WB     200072     // ushort[192*512] fragment-major Wb2
#define OFF_BIAS   249224     // float[256]
#define OFF_ELIST  249480     // uint[NE]
#define OFF_XB     1849480    // ushort[NN*64] node-major, 1.6M words each
#define OFF_HB     3449480
#define OFF_T1X    5049480
#define OFF_T1H    6649480
#define OFF_T2X    8249480
#define OFF_T2H    9849480
#define OFF_XH8    11449480   // char[NN*128] int8 interleaved X|H
#define OFF_T1XH8  13049480   // char[NN*128] int8 interleaved T1X|T1H
// overlays (consumed before their hosts are written):
#define OFF_HISTP  5049480    // uchar[250][50000] over T1X+T1H
#define OFF_COLEXC 8249480    // uchar[250][50000] over T2X+T2H
#define OFF_DEGP   13049480   // float[32][50000] over T1XH8

#define DCH    250            // dst chunks of 3200 edges
#define DCHUNK 3200
#define SCH    32             // deg chunks of 25000 edges
#define SCHUNK 25000
#define CNBLK  196
#define CBLK   1563
#define WBLK   48
#define FR_HIST (2 * DCH)              // 500
#define FR_DEG  (FR_HIST + 8 * SCH)    // 756
#define FR_CVT  (FR_DEG + CBLK)        // 2319
#define FR_ALL  (FR_CVT + WBLK)        // 2367

__device__ inline unsigned short f2bf(float f) {
  union { float f; unsigned u; } v; v.f = f;
  unsigned u = v.u;
  return (unsigned short)((u + 0x7FFFu + ((u >> 16) & 1u)) >> 16);
}
__device__ inline float bf2f(unsigned short u) {
  return __uint_as_float(((unsigned)u) << 16);
}
__device__ inline float sigm(float x) { return 1.f / (1.f + __expf(-x)); }
__device__ inline float tanh_(float x) { return 1.f - 2.f / (__expf(2.f * x) + 1.f); }

// signed int8 encode, fixed scale 4/127
__device__ inline unsigned f2q8(float f) {
  float c = fminf(fmaxf(f * QENC, -127.f), 127.f);
  int q = (int)rintf(c);
  return (unsigned)(q & 0xff);
}

// merged front-end: dst-hist + src-deg + cvt + wconv, one launch.
__global__ __launch_bounds__(256) void k_front(
    const int* __restrict__ src, const int* __restrict__ dst,
    const float* __restrict__ w,
    unsigned char* __restrict__ histp, float* __restrict__ degp,
    const float* __restrict__ X, const float* __restrict__ H,
    unsigned short* __restrict__ Xb, unsigned short* __restrict__ Hb,
    unsigned char* __restrict__ XH8,
    const float* __restrict__ Wx, const float* __restrict__ Wh,
    const float* __restrict__ bx, const float* __restrict__ bh,
    const float* __restrict__ bg,
    unsigned short* __restrict__ Wb2, float* __restrict__ bias) {
  __shared__ unsigned lds[6250];  // 25 KB (hist/deg roles only)
  const int t = threadIdx.x;
  const int bid = blockIdx.x;
  if (bid < FR_HIST) {
    const int c = bid >> 1, half = bid & 1, lo = half * 25000;
    for (int i = t; i < 6250; i += 256) lds[i] = 0u;
    __syncthreads();
    const int4* d4 = (const int4*)(dst + c * DCHUNK);
#pragma unroll
    for (int it = 0; it < 4; ++it) {
      int o4 = it * 256 + t;
      if (o4 < DCHUNK / 4) {
        int4 dv = d4[o4];
        int ds[4] = {dv.x, dv.y, dv.z, dv.w};
#pragma unroll
        for (int j = 0; j < 4; ++j) {
          int dr = ds[j] - lo;
          if ((unsigned)dr < 25000u)
            atomicAdd(&lds[dr >> 2], 1u << ((dr & 3) * 8));
        }
      }
    }
    __syncthreads();
    unsigned* hw = (unsigned*)(histp + c * 50000 + lo);
    for (int i = t; i < 6250; i += 256) hw[i] = lds[i];
  } else if (bid < FR_DEG) {
    const int idx = bid - FR_HIST;
    const int c = idx >> 3, e8 = idx & 7, lo = e8 * 6250;
    float* ldsf = (float*)lds;
    for (int i = t; i < 6250; i += 256) ldsf[i] = 0.f;
    __syncthreads();
    const int4* s4 = (const int4*)(src + c * SCHUNK);
    const float4* w4 = (const float4*)(w + c * SCHUNK);
    for (int it = 0; it < 25; ++it) {
      int o4 = it * 256 + t;
      if (o4 < SCHUNK / 4) {
        int4 sv = s4[o4];
        float4 wv = w4[o4];
        int ss[4] = {sv.x, sv.y, sv.z, sv.w};
        float ww[4] = {wv.x, wv.y, wv.z, wv.w};
#pragma unroll
        for (int j = 0; j < 4; ++j) {
          int sr = ss[j] - lo;
          if ((unsigned)sr < 6250u) atomicAdd(&ldsf[sr], ww[j]);
        }
      }
    }
    __syncthreads();
    float* dw = degp + c * 50000 + lo;
    for (int i = t; i < 6250; i += 256) dw[i] = ldsf[i];
  } else if (bid < FR_CVT) {
    int i = ((bid - FR_DEG) * 256 + t) * 8;
    if (i >= NN * 64) return;
    float4 x0 = *(const float4*)&X[i];
    float4 x1 = *(const float4*)&X[i + 4];
    float4 h0 = *(const float4*)&H[i];
    float4 h1 = *(const float4*)&H[i + 4];
    ushort8 xb, hb;
    xb[0] = f2bf(x0.x); xb[1] = f2bf(x0.y); xb[2] = f2bf(x0.z); xb[3] = f2bf(x0.w);
    xb[4] = f2bf(x1.x); xb[5] = f2bf(x1.y); xb[6] = f2bf(x1.z); xb[7] = f2bf(x1.w);
    hb[0] = f2bf(h0.x); hb[1] = f2bf(h0.y); hb[2] = f2bf(h0.z); hb[3] = f2bf(h0.w);
    hb[4] = f2bf(h1.x); hb[5] = f2bf(h1.y); hb[6] = f2bf(h1.z); hb[7] = f2bf(h1.w);
    *(ushort8*)&Xb[i] = xb;
    *(ushort8*)&Hb[i] = hb;
    int n = i >> 6, c = i & 63;
    unsigned xlo = f2q8(x0.x) | (f2q8(x0.y) << 8) | (f2q8(x0.z) << 16) | (f2q8(x0.w) << 24);
    unsigned xhi = f2q8(x1.x) | (f2q8(x1.y) << 8) | (f2q8(x1.z) << 16) | (f2q8(x1.w) << 24);
    unsigned hlo = f2q8(h0.x) | (f2q8(h0.y) << 8) | (f2q8(h0.z) << 16) | (f2q8(h0.w) << 24);
    unsigned hhi = f2q8(h1.x) | (f2q8(h1.y) << 8) | (f2q8(h1.z) << 16) | (f2q8(h1.w) << 24);
    *(uint2*)&XH8[n * 128 + c] = make_uint2(xlo, xhi);
    *(uint2*)&XH8[n * 128 + 64 + c] = make_uint2(hlo, hhi);
  } else {
    int idx = (bid - FR_CVT) * 256 + t;
    if (idx < 256) bias[idx] = bx[idx] + bh[idx] + bg[idx];
    if (idx >= 192 * 64) return;
    int word = idx >> 6, l = idx & 63;
    int cw = word & 3;
    int gk = word >> 2;
    int g = gk / 12, kc = gk - g * 12;
    int col = cw * 16 + (l & 15);
    int seg = kc >> 1;
    int kbase = (kc & 1) * 32 + (l >> 4) * 8;
    const float* Wsel = (seg < 3) ? Wx : Wh;
    int sch = (seg < 3) ? seg : seg - 3;
    ushort8 o8;
#pragma unroll
    for (int j = 0; j < 8; ++j) {
      float v = Wsel[((g * 3 + sch) * 64 + kbase + j) * 64 + col];
      o8[j] = f2bf(v);
    }
    *(ushort8*)&Wb2[idx * 8] = o8;
  }
}

__global__ __launch_bounds__(256) void k_colA(
    const unsigned char* __restrict__ histp, unsigned char* __restrict__ colexc,
    const float* __restrict__ degp, int* __restrict__ rowptr,
    int* __restrict__ bsum, float* __restrict__ dinv) {
  __shared__ int wsum[4];
  const int t = threadIdx.x, lane = t & 63, w = t >> 6;
  const int bin = blockIdx.x * 256 + t;
  int acc = 0;
  if (bin < NN) {
#pragma unroll 10
    for (int b = 0; b < DCH; ++b) {
      unsigned char c = histp[b * 50000 + bin];
      colexc[b * 50000 + bin] = (unsigned char)acc;
      acc += c;
    }
    float dacc = 0.f;
#pragma unroll 8
    for (int b = 0; b < SCH; ++b) dacc += degp[b * 50000 + bin];
    dinv[bin] = (dacc > 0.f) ? rsqrtf(dacc) : 0.f;
  }
  int val = acc;
#pragma unroll
  for (int off = 1; off < 64; off <<= 1) {
    int u = __shfl_up(val, off, 64);
    if (lane >= off) val += u;
  }
  if (lane == 63) wsum[w] = val;
  __syncthreads();
  int wb = 0;
#pragma unroll
  for (int i = 0; i < 4; ++i) wb += (i < w) ? wsum[i] : 0;
  int incl = wb + val;
  if (bin < NN) rowptr[bin + 1] = incl;
  if (t == 255) bsum[blockIdx.x] = incl;
}

__global__ __launch_bounds__(256) void k_scanB2(int* __restrict__ bsum,
                                                int* __restrict__ rowptr) {
  __shared__ int wsum[4];
  const int t = threadIdx.x, lane = t & 63, w = t >> 6;
  int v = (t < CNBLK) ? bsum[t] : 0;
  int val = v;
#pragma unroll
  for (int off = 1; off < 64; off <<= 1) {
    int u = __shfl_up(val, off, 64);
    if (lane >= off) val += u;
  }
  if (lane == 63) wsum[w] = val;
  __syncthreads();
  int wb = 0;
#pragma unroll
  for (int i = 0; i < 4; ++i) wb += (i < w) ? wsum[i] : 0;
  int incl = wb + val;
  if (t < CNBLK) bsum[t] = incl - v;
  if (t == 0) rowptr[0] = 0;
}

__global__ __launch_bounds__(256) void k_scanC2(int* __restrict__ rowptr,
                                                const int* __restrict__ bsum) {
  int i = blockIdx.x * 256 + threadIdx.x;
  if (i < NN) rowptr[i + 1] += bsum[blockIdx.x];
}

__global__ __launch_bounds__(256) void k_scat(
    const int* __restrict__ src, const int* __restrict__ dst,
    const float* __restrict__ w, const float* __restrict__ dinv,
    const int* __restrict__ rowptr, const unsigned char* __restrict__ colexc,
    unsigned* __restrict__ elist) {
  __shared__ unsigned lds[6250];
  const int t = threadIdx.x, bid = blockIdx.x;
  const int c = bid >> 1, half = bid & 1, lo = half * 25000;
  for (int i = t; i < 6250; i += 256) lds[i] = 0u;
  __syncthreads();
  const int4* s4 = (const int4*)(src + c * DCHUNK);
  const int4* d4 = (const int4*)(dst + c * DCHUNK);
  const float4* w4 = (const float4*)(w + c * DCHUNK);
#pragma unroll
  for (int it = 0; it < 4; ++it) {
    int o4 = it * 256 + t;
    if (o4 < DCHUNK / 4) {
      int4 sv = s4[o4];
      int4 dv = d4[o4];
      float4 wv = w4[o4];
      int ss[4] = {sv.x, sv.y, sv.z, sv.w};
      int dd[4] = {dv.x, dv.y, dv.z, dv.w};
      float ww[4] = {wv.x, wv.y, wv.z, wv.w};
#pragma unroll
      for (int j = 0; j < 4; ++j) {
        int d = dd[j];
        int dr = d - lo;
        if ((unsigned)dr < 25000u) {
          int s = ss[j];
          float nm = -dinv[s] * ww[j] * dinv[d];
          unsigned old = atomicAdd(&lds[dr >> 2], 1u << ((dr & 3) * 8));
          int rank = (int)((old >> ((dr & 3) * 8)) & 0xffu);
          int pos = rowptr[d] + (int)colexc[c * 50000 + d] + rank;
          elist[pos] = (((unsigned)f2bf(nm)) << 16) | (unsigned)s;
        }
      }
    }
  }
}

// prop (R21-proven): signed int8 interleaved gather, 8 edges/instr.
__global__ __launch_bounds__(256) void k_prop(
    const int* __restrict__ rowptr, const unsigned* __restrict__ elist,
    const uint4* __restrict__ inP8,
    unsigned short* __restrict__ outX, unsigned short* __restrict__ outH,
    uint4* __restrict__ outP8,
    const unsigned short* __restrict__ baseX, const unsigned short* __restrict__ baseH,
    int mode) {
  const int n = blockIdx.x * 4 + (threadIdx.x >> 6);
  const int l = threadIdx.x & 63;
  const int es = l >> 3;
  const int p = l & 7;
  if (n >= NN) return;
  const int beg = rowptr[n], end = rowptr[n + 1];
  float acc[16];
#pragma unroll
  for (int j = 0; j < 16; ++j) acc[j] = 0.f;
  for (int i0 = beg; i0 < end; i0 += 16) {
    int ie0 = i0 + es, ie1 = i0 + 8 + es;
    unsigned u0 = (ie0 < end) ? elist[ie0] : 0u;
    unsigned u1 = (ie1 < end) ? elist[ie1] : 0u;
    int s0 = (int)(u0 & 0xffffu), s1 = (int)(u1 & 0xffffu);
    float n0 = __uint_as_float(u0 & 0xffff0000u) * QDEC;
    float n1 = __uint_as_float(u1 & 0xffff0000u) * QDEC;
    uint4 v0 = inP8[s0 * 8 + p];
    uint4 v1 = inP8[s1 * 8 + p];
    unsigned w0[4] = {v0.x, v0.y, v0.z, v0.w};
    unsigned w1[4] = {v1.x, v1.y, v1.z, v1.w};
#pragma unroll
    for (int wd = 0; wd < 4; ++wd) {
#pragma unroll
      for (int bt = 0; bt < 4; ++bt) {
        float g0 = (float)((int)(char)(w0[wd] >> (bt * 8)));
        float g1 = (float)((int)(char)(w1[wd] >> (bt * 8)));
        acc[wd * 4 + bt] += n0 * g0 + n1 * g1;
      }
    }
  }
#pragma unroll
  for (int mask = 8; mask <= 32; mask <<= 1)
#pragma unroll
    for (int j = 0; j < 16; ++j) acc[j] += __shfl_xor(acc[j], mask, 64);

  if (es != 0) return;
  const int chbase = (p & 3) * 16;
  unsigned short* outT = (p < 4) ? outX : outH;
  const unsigned short* baseT = (p < 4) ? baseX : baseH;
  float vals[16];
  if (mode) {
    ushort8 b0 = *(const ushort8*)&baseT[n * 64 + chbase];
    ushort8 b1 = *(const ushort8*)&baseT[n * 64 + chbase + 8];
#pragma unroll
    for (int j = 0; j < 8; ++j) {
      vals[j] = 2.f * acc[j] - bf2f(b0[j]);
      vals[8 + j] = 2.f * acc[8 + j] - bf2f(b1[j]);
    }
  } else {
#pragma unroll
    for (int j = 0; j < 16; ++j) vals[j] = acc[j];
  }
  ushort8 o0, o1;
#pragma unroll
  for (int j = 0; j < 8; ++j) { o0[j] = f2bf(vals[j]); o1[j] = f2bf(vals[8 + j]); }
  *(ushort8*)&outT[n * 64 + chbase] = o0;
  *(ushort8*)&outT[n * 64 + chbase + 8] = o1;
  if (!mode) {
    unsigned wv[4];
#pragma unroll
    for (int wd = 0; wd < 4; ++wd) {
      unsigned r = 0;
#pragma unroll
      for (int bt = 0; bt < 4; ++bt) r |= f2q8(vals[wd * 4 + bt]) << (bt * 8);
      wv[wd] = r;
    }
    uint4 o8; o8.x = wv[0]; o8.y = wv[1]; o8.z = wv[2]; o8.w = wv[3];
    outP8[n * 8 + p] = o8;
  }
}

// MFMA gates (R21-proven): 32-row tiles, 24KB LDS stage (swizzled), node-major
// A, fragment-major B, C prefetched, epilogue in registers.
__global__ __launch_bounds__(256, 6) void k_gates(
    const unsigned short* __restrict__ Xb, const unsigned short* __restrict__ Hb,
    const unsigned short* __restrict__ T1X, const unsigned short* __restrict__ T1H,
    const unsigned short* __restrict__ T2X, const unsigned short* __restrict__ T2H,
    const unsigned short* __restrict__ Wb2, const float* __restrict__ C,
    const float* __restrict__ bias, const float* __restrict__ wc,
    float* __restrict__ out) {
  __shared__ unsigned short A[6 * 32 * 64];  // 24 KB
  const int t = threadIdx.x;
  const int cw = t >> 6;
  const int l = t & 63;
  const int base = blockIdx.x * 32;
  const int lr = l & 15;
  const int cc = cw * 16 + lr;

  float cpre[2][4];
#pragma unroll
  for (int rb = 0; rb < 2; ++rb)
#pragma unroll
    for (int q = 0; q < 4; ++q) {
      int n = base + rb * 16 + (l >> 4) * 4 + q;
      int nc = (n < NN) ? n : NN - 1;
      cpre[rb][q] = C[nc * 64 + cc];
    }

  const unsigned short* segp[6] = {Xb, T1X, T2X, Hb, T1H, T2H};
  {
    const int r = t >> 3, g0 = t & 7;
    const int gsw = g0 ^ (r & 7);
    int n = base + r;
    int nc = (n < NN) ? n : NN - 1;
    ushort8 st[6];
#pragma unroll
    for (int seg = 0; seg < 6; ++seg)
      st[seg] = *(const ushort8*)&segp[seg][nc * 64 + gsw * 8];
#pragma unroll
    for (int seg = 0; seg < 6; ++seg)
      *(ushort8*)&A[(seg * 256 + t) * 8] = st[seg];
  }
  __syncthreads();

  f32x4 acc[4][2];
#pragma unroll
  for (int g = 0; g < 4; ++g) {
    acc[g][0] = (f32x4){0.f, 0.f, 0.f, 0.f};
    acc[g][1] = (f32x4){0.f, 0.f, 0.f, 0.f};
  }

#pragma unroll
  for (int kc = 0; kc < 12; ++kc) {
    const int seg = kc >> 1;
    const int slot = ((kc & 1) * 4 + (l >> 4)) ^ (lr & 7);
    short8 a[2];
#pragma unroll
    for (int rb = 0; rb < 2; ++rb) {
      int row = rb * 16 + lr;
      a[rb] = *(const short8*)&A[((seg * 32 + row) * 8 + slot) * 8];
    }
#pragma unroll
    for (int g = 0; g < 4; ++g) {
      short8 b = *(const short8*)&Wb2[(((g * 12 + kc) * 4 + cw) << 9) + l * 8];
      acc[g][0] = __builtin_amdgcn_mfma_f32_16x16x32_bf16(a[0], b, acc[g][0], 0, 0, 0);
      acc[g][1] = __builtin_amdgcn_mfma_f32_16x16x32_bf16(a[1], b, acc[g][1], 0, 0, 0);
    }
  }

  const float bI = bias[cc],       bF = bias[64 + cc];
  const float bT = bias[128 + cc], bO = bias[192 + cc];
  const float wI = wc[cc], wF = wc[64 + cc], wO = wc[128 + cc];
#pragma unroll
  for (int rb = 0; rb < 2; ++rb) {
#pragma unroll
    for (int q = 0; q < 4; ++q) {
      int n = base + rb * 16 + (l >> 4) * 4 + q;
      if (n >= NN) continue;
      float cv = cpre[rb][q];
      float pI = acc[0][rb][q] + bI + wI * cv;
      float pF = acc[1][rb][q] + bF + wF * cv;
      float pT = acc[2][rb][q] + bT;
      float I = sigm(pI);
      float F = sigm(pF);
      float T = tanh_(pT);
      float Cn = F * cv + I * T;
      float pO = acc[3][rb][q] + bO + wO * Cn;
      float O = sigm(pO);
      out[n * 64 + cc] = O * tanh_(Cn);
      out[NN * 64 + n * 64 + cc] = Cn;
    }
  }
}

extern "C" void kernel_launch(void* const* d_in, const int* in_sizes, int n_in,
                              void* d_out, int out_size, void* d_ws, size_t ws_size,
                              hipStream_t stream) {
  const float* X  = (const float*)d_in[0];
  const int*   ei = (const int*)d_in[1];
  const float* ew = (const float*)d_in[2];
  const float* H  = (const float*)d_in[3];
  const float* C  = (const float*)d_in[4];
  const float* Wx = (const float*)d_in[5];
  const float* bx = (const float*)d_in[6];
  const float* Wh = (const float*)d_in[7];
  const float* bh = (const float*)d_in[8];
  const float* wc = (const float*)d_in[9];
  const float* bg = (const float*)d_in[10];
  float* out = (float*)d_out;
  float* ws = (float*)d_ws;

  const int* src = ei;
  const int* dst = ei + NE;
  float* dinv = ws + OFF_DEG;
  int* bsum = (int*)(ws + OFF_BSUM);
  int* rowptr = (int*)(ws + OFF_ROWPTR);
  unsigned short* Wb2 = (unsigned short*)(ws + OFF_WB);
  float* bias = ws + OFF_BIAS;
  unsigned* elist = (unsigned*)(ws + OFF_ELIST);
  unsigned char* histp = (unsigned char*)(ws + OFF_HISTP);
  unsigned char* colexc = (unsigned char*)(ws + OFF_COLEXC);
  float* degp = ws + OFF_DEGP;
  unsigned short* Xb  = (unsigned short*)(ws + OFF_XB);
  unsigned short* Hb  = (unsigned short*)(ws + OFF_HB);
  unsigned short* T1X = (unsigned short*)(ws + OFF_T1X);
  unsigned short* T1H = (unsigned short*)(ws + OFF_T1H);
  unsigned short* T2X = (unsigned short*)(ws + OFF_T2X);
  unsigned short* T2H = (unsigned short*)(ws + OFF_T2H);
  unsigned char* XH8   = (unsigned char*)(ws + OFF_XH8);
  unsigned char* T1XH8 = (unsigned char*)(ws + OFF_T1XH8);

  k_front<<<FR_ALL, 256, 0, stream>>>(src, dst, ew, histp, degp,
                                      X, H, Xb, Hb, XH8,
                                      Wx, Wh, bx, bh, bg, Wb2, bias);
  k_colA<<<CNBLK, 256, 0, stream>>>(histp, colexc, degp, rowptr, bsum, dinv);
  k_scanB2<<<1, 256, 0, stream>>>(bsum, rowptr);
  k_scanC2<<<CNBLK, 256, 0, stream>>>(rowptr, bsum);
  k_scat<<<2 * DCH, 256, 0, stream>>>(src, dst, ew, dinv, rowptr, colexc, elist);
  k_prop<<<NN / 4, 256, 0, stream>>>(rowptr, elist, (const uint4*)XH8,
                                     T1X, T1H, (uint4*)T1XH8,
                                     nullptr, nullptr, 0);
  k_prop<<<NN / 4, 256, 0, stream>>>(rowptr, elist, (const uint4*)T1XH8,
                                     T2X, T2H, nullptr, Xb, Hb, 1);
  k_gates<<<(NN + 31) / 32, 256, 0, stream>>>(Xb, Hb, T1X, T1H, T2X, T2H,
                                              Wb2, C, bias, wc, out);
}